// Round 8
// baseline (640.385 us; speedup 1.0000x reference)
//
#include <hip/hip_runtime.h>
#include <hip/hip_bf16.h>
#include <math.h>

// ---------------------------------------------------------------------------
// Real spherical harmonics, l_max = 8. Output (N, 81) float32, row-major.
//
// R8: 1 producer : 2 consumer waves (TPB=192), nt stores restored.
//   - Ledger: dur ~= fill(411, harness) + tiny-restore tax(~100, harness)
//     + kernel(~110-125 vs 103us write floor). Only mover in 7 rounds was
//     R6's role split (+20us) => store-issue duty cycle is the empirical
//     lever, contradicting queue-depth arithmetic. Follow the gradient:
//     double pure-store waves 3->6 per CU; each consumer streams half a
//     tile, halving its non-store (ds_read/handshake) phase fraction.
//   - LDS 41.5KB unchanged -> 3 WGs/CU, 9 waves. nt restored (R6>=R7).
//   - Flags: ready[2] (producer-only writer); doneA[2]/doneB[2] (one writer
//     each); producer polls both. No s_barrier in loop.
//   - Predict: duty-cycle cap -> dur 637 -> ~600-612. Unchanged -> kernel
//     is at write roofline inside fixed harness envelope; declare ROOFLINE.
// ---------------------------------------------------------------------------

#define LMAX 8
#define NSH  81                    // (LMAX+1)^2
#define PTS  64                    // points per tile
#define TPB  192                   // 1 producer + 2 consumer waves
#define NWG  (3 * 256)             // 3 WGs/CU (LDS-capped) x 256 CUs
#define NF4  (PTS * NSH / 4)       // 1296 float4 per tile
#define HF4  (NF4 / 2)             // 648 float4 per consumer half
#define F4PC (HF4 / 64)            // 10 full float4 per consumer lane
#define REMC (HF4 - F4PC * 64)     // 8 leftover float4 (lanes 0..7)

typedef float f32x4 __attribute__((ext_vector_type(4)));

// ---- compile-time k(l,m) table (includes sqrt(2) for m>0) ------------------
constexpr double c_sqrt(double x) {
    double g = (x > 1.0) ? x : 1.0;
    for (int i = 0; i < 80; ++i) g = 0.5 * (g + x / g);
    return g;
}
constexpr double c_fact(int n) {
    double r = 1.0;
    for (int i = 2; i <= n; ++i) r *= (double)i;
    return r;
}
struct KTab {
    float k[LMAX + 1][LMAX + 1];   // k[l][m], m<=l
    constexpr KTab() : k{} {
        for (int l = 0; l <= LMAX; ++l)
            for (int m = 0; m <= l; ++m) {
                double v = c_sqrt((2.0 * l + 1.0) / (4.0 * 3.14159265358979323846)
                                  * c_fact(l - m) / c_fact(l + m));
                if (m > 0) v *= 1.41421356237309504880;   // sqrt(2)
                k[l][m] = (float)v;
            }
    }
};
constexpr KTab KT{};

__device__ __forceinline__ void compiler_fence() {
    asm volatile("" ::: "memory");
}
__device__ __forceinline__ void lds_drain() {
    asm volatile("s_waitcnt lgkmcnt(0)" ::: "memory");
}

__device__ __forceinline__ void compute_row(float x, float y, float z, float* row) {
    const float r2xy = x * x + y * y;
    const float r    = sqrtf(r2xy + z * z);
    const float rxy  = sqrtf(r2xy);
    const float ct   = z / r;
    const float st   = rxy / r;
    const float irxy = (rxy > 0.0f) ? (1.0f / rxy) : 0.0f;
    const float cp   = x * irxy;
    const float sp   = y * irxy;

    float cm[LMAX + 1], sm[LMAX + 1];
    cm[0] = 1.0f; sm[0] = 0.0f;
#pragma unroll
    for (int m = 1; m <= LMAX; ++m) {
        cm[m] = cm[m - 1] * cp - sm[m - 1] * sp;
        sm[m] = sm[m - 1] * cp + cm[m - 1] * sp;
    }

    float P[LMAX + 1][LMAX + 1];
    P[0][0] = 1.0f;
#pragma unroll
    for (int m = 1; m <= LMAX; ++m)
        P[m][m] = (float)(2 * m - 1) * st * P[m - 1][m - 1];
#pragma unroll
    for (int m = 0; m < LMAX; ++m)
        P[m + 1][m] = (float)(2 * m + 1) * ct * P[m][m];
#pragma unroll
    for (int m = 0; m <= LMAX; ++m) {
#pragma unroll
        for (int l = m + 2; l <= LMAX; ++l) {
            P[l][m] = ((float)(2 * l - 1) * ct * P[l - 1][m]
                       - (float)(l + m - 1) * P[l - 2][m]) * (1.0f / (float)(l - m));
        }
    }

    // row stride 81 floats: bank = (17*t + j) % 32 -> 2-way across 64 lanes (free)
#pragma unroll
    for (int l = 0; l <= LMAX; ++l) {
        const int base = l * l + l;
        row[base] = KT.k[l][0] * P[l][0];
#pragma unroll
        for (int m = 1; m <= l; ++m) {
            const float kp = KT.k[l][m] * P[l][m];
            row[base + m] = kp * cm[m];
            row[base - m] = kp * sm[m];
        }
    }
}

__global__ __launch_bounds__(TPB)
void sh_kernel(const float* __restrict__ xyz, float* __restrict__ out, int n) {
    __shared__ float data[2][PTS * NSH];   // 2 x 20736 B
    __shared__ int   flags[6];   // [0..1]=ready(b); [2..3]=doneA(b); [4..5]=doneB(b)

    const int t    = threadIdx.x & 63;
    const int wave = threadIdx.x >> 6;        // 0 = producer, 1..2 = consumers
    const int ntiles = (n + PTS - 1) / PTS;   // grid <= ntiles guaranteed

    if (threadIdx.x == 0) {
#pragma unroll
        for (int i = 0; i < 6; ++i) flags[i] = 0;
    }
    __syncthreads();   // one-time; makes flag init visible to all waves

    if (wave == 0) {
        // ------------------------- producer wave ---------------------------
        int tile = blockIdx.x;
        int j = 0;
        float x = 0.0f, y = 0.0f, z = 1.0f;
        {
            const int p = tile * PTS + t;
            if (p < n) { x = xyz[3*p]; y = xyz[3*p+1]; z = xyz[3*p+2]; }
        }
        for (;;) {
            const int next_tile = tile + gridDim.x;
            // prefetch next tile's xyz under this tile's compute
            float nx = 0.0f, ny = 0.0f, nz = 1.0f;
            if (next_tile < ntiles) {
                const int np = next_tile * PTS + t;
                if (np < n) { nx = xyz[3*np]; ny = xyz[3*np+1]; nz = xyz[3*np+2]; }
            }
            const int b = j & 1;
            const int u = j >> 1;
            // wait until BOTH consumers released buffer b
            {
                volatile int* dA = &flags[2 + b];
                volatile int* dB = &flags[4 + b];
                while (*dA != u || *dB != u) __builtin_amdgcn_s_sleep(2);
            }
            compiler_fence();
            compute_row(x, y, z, &data[b][t * NSH]);
            lds_drain();                       // data writes complete before flag
            if (t == 0) flags[b] = u + 1;      // publish ready
            ++j;
            if (next_tile >= ntiles) break;
            tile = next_tile;
            x = nx; y = ny; z = nz;
        }
    } else {
        // ---------------------- consumer (store) waves ----------------------
        const int ch = wave - 1;               // 0: first half, 1: second half
        int tile = blockIdx.x;
        int j = 0;
        for (;;) {
            const int b = j & 1;
            const int u = j >> 1;
            {
                volatile int* rd = &flags[b];
                while (*rd != u + 1) __builtin_amdgcn_s_sleep(2);
            }
            compiler_fence();
            const int p0    = tile * PTS;
            const int valid = (n - p0 < PTS) ? (n - p0) : PTS;
            float* op = out + (size_t)p0 * NSH;
            if (valid == PTS) {
                f32x4* o4 = (f32x4*)op + ch * HF4;
                const f32x4* l4 = (const f32x4*)data[b] + ch * HF4;
                // stage all ds_reads into distinct regs, then pure store burst
                f32x4 buf[F4PC];
#pragma unroll
                for (int i = 0; i < F4PC; ++i)
                    buf[i] = l4[t + i * 64];
                f32x4 bufr = {0.f, 0.f, 0.f, 0.f};
                if (t < REMC) bufr = l4[F4PC * 64 + t];
#pragma unroll
                for (int i = 0; i < F4PC; ++i)
                    __builtin_nontemporal_store(buf[i], &o4[t + i * 64]);
                if (t < REMC)
                    __builtin_nontemporal_store(bufr, &o4[F4PC * 64 + t]);
            } else {
                const int nf = valid * NSH;
                for (int i = t + ch * 64; i < nf; i += 128) {
                    float v = data[b][i];
                    __builtin_nontemporal_store(v, &op[i]);
                }
            }
            lds_drain();                            // ds_reads done before release
            if (t == 0) flags[2 + 2 * ch + b] = u + 1;  // single-writer release
            ++j;
            const int next_tile = tile + gridDim.x;
            if (next_tile >= ntiles) break;
            tile = next_tile;
        }
    }
}

extern "C" void kernel_launch(void* const* d_in, const int* in_sizes, int n_in,
                              void* d_out, int out_size, void* d_ws, size_t ws_size,
                              hipStream_t stream) {
    const float* xyz = (const float*)d_in[0];
    float*       out = (float*)d_out;
    const int n = in_sizes[0] / 3;
    const int ntiles = (n + PTS - 1) / PTS;
    const int grid = (ntiles < NWG) ? ntiles : NWG;   // grid <= ntiles: no idle WGs
    if (grid > 0) {
        hipLaunchKernelGGL(sh_kernel, dim3(grid), dim3(TPB), 0, stream, xyz, out, n);
    }
}

// Round 9
// 628.444 us; speedup vs baseline: 1.0190x; 1.0190x over previous
//
#include <hip/hip_runtime.h>
#include <hip/hip_bf16.h>
#include <math.h>

// ---------------------------------------------------------------------------
// Real spherical harmonics, l_max = 8. Output (N, 81) float32, row-major.
//
// R9 == R6 (best measured, 629us): producer/consumer wave specialization.
//   - Final ledger across 8 structural variants:
//       monolithic (6 variants): 648-658 | P/C 1:1 nt: 629 (best)
//       P/C 1:1 plain: 637       | P/C 1:2 nt: 640
//   - Decomposition: dur ~= harness-fill(411) + harness tiny-restore(~100)
//     + kernel(~118 vs 103us write-roofline floor). All kernel-side deltas
//     since R6 are within fill-noise (+-10us) => kernel is at the write-BW
//     limit; the rest of dur_us is fixed harness work.
//   - Structure: wave 0 computes tiles into double-buffered LDS; wave 1 does
//     ds_read_b128 + back-to-back nt global_store_dwordx4 (fill-kernel
//     mimic). LDS epoch-flag handshake + s_sleep; no s_barrier in loop =>
//     no vmcnt drain on the store wave. 3 WGs/CU (41.5KB LDS).
// ---------------------------------------------------------------------------

#define LMAX 8
#define NSH  81                    // (LMAX+1)^2
#define PTS  64                    // points per tile
#define TPB  128                   // 2 waves per workgroup
#define NWG  (3 * 256)             // 3 WGs/CU (LDS-capped) x 256 CUs
#define NF4  (PTS * NSH / 4)       // 1296 float4 per tile
#define F4PT (NF4 / 64)            // 20 full float4 per lane
#define REM  (NF4 - F4PT * 64)     // 16 leftover float4 (lanes 0..15)

typedef float f32x4 __attribute__((ext_vector_type(4)));

// ---- compile-time k(l,m) table (includes sqrt(2) for m>0) ------------------
constexpr double c_sqrt(double x) {
    double g = (x > 1.0) ? x : 1.0;
    for (int i = 0; i < 80; ++i) g = 0.5 * (g + x / g);
    return g;
}
constexpr double c_fact(int n) {
    double r = 1.0;
    for (int i = 2; i <= n; ++i) r *= (double)i;
    return r;
}
struct KTab {
    float k[LMAX + 1][LMAX + 1];   // k[l][m], m<=l
    constexpr KTab() : k{} {
        for (int l = 0; l <= LMAX; ++l)
            for (int m = 0; m <= l; ++m) {
                double v = c_sqrt((2.0 * l + 1.0) / (4.0 * 3.14159265358979323846)
                                  * c_fact(l - m) / c_fact(l + m));
                if (m > 0) v *= 1.41421356237309504880;   // sqrt(2)
                k[l][m] = (float)v;
            }
    }
};
constexpr KTab KT{};

__device__ __forceinline__ void compiler_fence() {
    asm volatile("" ::: "memory");
}
__device__ __forceinline__ void lds_drain() {
    asm volatile("s_waitcnt lgkmcnt(0)" ::: "memory");
}

__device__ __forceinline__ void compute_row(float x, float y, float z, float* row) {
    const float r2xy = x * x + y * y;
    const float r    = sqrtf(r2xy + z * z);
    const float rxy  = sqrtf(r2xy);
    const float ct   = z / r;
    const float st   = rxy / r;
    const float irxy = (rxy > 0.0f) ? (1.0f / rxy) : 0.0f;
    const float cp   = x * irxy;
    const float sp   = y * irxy;

    float cm[LMAX + 1], sm[LMAX + 1];
    cm[0] = 1.0f; sm[0] = 0.0f;
#pragma unroll
    for (int m = 1; m <= LMAX; ++m) {
        cm[m] = cm[m - 1] * cp - sm[m - 1] * sp;
        sm[m] = sm[m - 1] * cp + cm[m - 1] * sp;
    }

    float P[LMAX + 1][LMAX + 1];
    P[0][0] = 1.0f;
#pragma unroll
    for (int m = 1; m <= LMAX; ++m)
        P[m][m] = (float)(2 * m - 1) * st * P[m - 1][m - 1];
#pragma unroll
    for (int m = 0; m < LMAX; ++m)
        P[m + 1][m] = (float)(2 * m + 1) * ct * P[m][m];
#pragma unroll
    for (int m = 0; m <= LMAX; ++m) {
#pragma unroll
        for (int l = m + 2; l <= LMAX; ++l) {
            P[l][m] = ((float)(2 * l - 1) * ct * P[l - 1][m]
                       - (float)(l + m - 1) * P[l - 2][m]) * (1.0f / (float)(l - m));
        }
    }

    // row stride 81 floats: bank = (17*t + j) % 32 -> 2-way across 64 lanes (free)
#pragma unroll
    for (int l = 0; l <= LMAX; ++l) {
        const int base = l * l + l;
        row[base] = KT.k[l][0] * P[l][0];
#pragma unroll
        for (int m = 1; m <= l; ++m) {
            const float kp = KT.k[l][m] * P[l][m];
            row[base + m] = kp * cm[m];
            row[base - m] = kp * sm[m];
        }
    }
}

__global__ __launch_bounds__(TPB)
void sh_kernel(const float* __restrict__ xyz, float* __restrict__ out, int n) {
    __shared__ float data[2][PTS * NSH];   // 2 x 20736 B
    __shared__ int   flags[4];             // [0],[1]=ready(b) ; [2],[3]=done(b)

    const int t    = threadIdx.x & 63;
    const int wave = threadIdx.x >> 6;
    const int ntiles = (n + PTS - 1) / PTS;   // grid <= ntiles guaranteed

    if (threadIdx.x == 0) {
        flags[0] = 0; flags[1] = 0; flags[2] = 0; flags[3] = 0;
    }
    __syncthreads();   // one-time; makes flag init visible to both waves

    if (wave == 0) {
        // ------------------------- producer wave ---------------------------
        int tile = blockIdx.x;
        int j = 0;
        float x = 0.0f, y = 0.0f, z = 1.0f;
        {
            const int p = tile * PTS + t;
            if (p < n) { x = xyz[3*p]; y = xyz[3*p+1]; z = xyz[3*p+2]; }
        }
        for (;;) {
            const int next_tile = tile + gridDim.x;
            // prefetch next tile's xyz under this tile's compute
            float nx = 0.0f, ny = 0.0f, nz = 1.0f;
            if (next_tile < ntiles) {
                const int np = next_tile * PTS + t;
                if (np < n) { nx = xyz[3*np]; ny = xyz[3*np+1]; nz = xyz[3*np+2]; }
            }
            const int b = j & 1;
            const int u = j >> 1;
            // wait until consumer released buffer b (usage u complete count == u)
            {
                volatile int* dn = &flags[2 + b];
                while (*dn != u) __builtin_amdgcn_s_sleep(2);
            }
            compiler_fence();
            compute_row(x, y, z, &data[b][t * NSH]);
            lds_drain();                       // data writes complete before flag
            if (t == 0) flags[b] = u + 1;      // publish ready
            ++j;
            if (next_tile >= ntiles) break;
            tile = next_tile;
            x = nx; y = ny; z = nz;
        }
    } else {
        // ------------------------- consumer (store) wave --------------------
        int tile = blockIdx.x;
        int j = 0;
        for (;;) {
            const int b = j & 1;
            const int u = j >> 1;
            {
                volatile int* rd = &flags[b];
                while (*rd != u + 1) __builtin_amdgcn_s_sleep(2);
            }
            compiler_fence();
            const int p0    = tile * PTS;
            const int valid = (n - p0 < PTS) ? (n - p0) : PTS;
            float* op = out + (size_t)p0 * NSH;
            if (valid == PTS) {
                f32x4* o4 = (f32x4*)op;
                const f32x4* l4 = (const f32x4*)data[b];
                // stage all ds_reads into distinct regs, then pure store burst
                f32x4 buf[F4PT];
#pragma unroll
                for (int i = 0; i < F4PT; ++i)
                    buf[i] = l4[t + i * 64];
                f32x4 bufr = {0.f, 0.f, 0.f, 0.f};
                if (t < REM) bufr = l4[F4PT * 64 + t];
#pragma unroll
                for (int i = 0; i < F4PT; ++i)
                    __builtin_nontemporal_store(buf[i], &o4[t + i * 64]);
                if (t < REM)
                    __builtin_nontemporal_store(bufr, &o4[F4PT * 64 + t]);
            } else {
                const int nf = valid * NSH;
                for (int i = t; i < nf; i += 64) {
                    float v = data[b][i];
                    __builtin_nontemporal_store(v, &op[i]);
                }
            }
            lds_drain();                       // ds_reads complete before release
            if (t == 0) flags[2 + b] = u + 1;  // release buffer
            ++j;
            const int next_tile = tile + gridDim.x;
            if (next_tile >= ntiles) break;
            tile = next_tile;
        }
    }
}

extern "C" void kernel_launch(void* const* d_in, const int* in_sizes, int n_in,
                              void* d_out, int out_size, void* d_ws, size_t ws_size,
                              hipStream_t stream) {
    const float* xyz = (const float*)d_in[0];
    float*       out = (float*)d_out;
    const int n = in_sizes[0] / 3;
    const int ntiles = (n + PTS - 1) / PTS;
    const int grid = (ntiles < NWG) ? ntiles : NWG;   // grid <= ntiles: no idle WGs
    if (grid > 0) {
        hipLaunchKernelGGL(sh_kernel, dim3(grid), dim3(TPB), 0, stream, xyz, out, n);
    }
}